// Round 1
// baseline (105.475 us; speedup 1.0000x reference)
//
#include <hip/hip_runtime.h>

// Sizes
// M0E=64, M1O=32, M1E=32, M0O=16, IN_DIM = 64 + 96 + 96 + 16 = 272
// W layout (flat): w0e [96][64] @0      scale 1/sqrt(96)
//                  w1o [128][32] @6144  scale 1/sqrt(128)
//                  w1e [80][32] @10240  scale 1/sqrt(80)
//                  w0o [48][16] @12800  scale 1/sqrt(48)
// x row layout: x0e[0..63], x1o[j*3+d]@64, x1e[j*3+d]@160, x0o@256
// Z row layout per (b,n,c): [y0e(64) | y1o r=o*3+d (96) | y1e (96) | y0o(16)] = 272
// out[b][m][n][o]: for fixed (b,m) a contiguous slab of 128*272=34816 floats = 8704 float4

constexpr float INV_S3 = 0.57735026918962576f; // 1/sqrt(3)
constexpr float INV_S2 = 0.70710678118654752f; // 1/sqrt(2)
constexpr float SC0E = 0.10206207261596577f;   // 1/sqrt(96)
constexpr float SC1O = 0.08838834764831845f;   // 1/sqrt(128)
constexpr float SC1E = 0.11180339887498949f;   // 1/sqrt(80)
constexpr float SC0O = 0.14433756729740643f;   // 1/sqrt(48)

__global__ __launch_bounds__(256) void stage_a(const float* __restrict__ in_,
                                               const float* __restrict__ weight,
                                               float* __restrict__ Z) {
    __shared__ float xs[272];
    __shared__ float w0e[96 * 64];
    __shared__ float w1o[128 * 32];
    __shared__ float w1e[80 * 32];
    __shared__ float w0o[48 * 16];
    __shared__ float o0e[4][96];
    __shared__ float o1o[4][128][3];
    __shared__ float o1e[4][80][3];
    __shared__ float o0o[4][48];

    const int tid = threadIdx.x;
    const int row = blockIdx.x; // b*128 + n, 512 rows
    const float* x = in_ + row * 272;

    for (int i = tid; i < 272; i += 256) xs[i] = x[i];
    for (int i = tid; i < 6144; i += 256) w0e[i] = weight[i] * SC0E;
    for (int i = tid; i < 4096; i += 256) w1o[i] = weight[6144 + i] * SC1O;
    for (int i = tid; i < 2560; i += 256) w1e[i] = weight[10240 + i] * SC1E;
    for (int i = tid; i < 768;  i += 256) w0o[i] = weight[12800 + i] * SC0O;
    __syncthreads();

    // Build out*[c] for sh = e_c (c=0 -> sh0=1; c>=1 -> sh1 = e_{c-1})
    // out0e[c][k]: k<64: x0e*sh0 ; k>=64: (x1o[k-64]·sh1)/sqrt3
    for (int idx = tid; idx < 4 * 96; idx += 256) {
        int c = idx / 96, k = idx % 96;
        float v = 0.f;
        if (k < 64) { if (c == 0) v = xs[k]; }
        else        { if (c >= 1) v = xs[64 + (k - 64) * 3 + (c - 1)] * INV_S3; }
        o0e[c][k] = v;
    }
    // out1o[c][k][d]: k<64: x0e[k]*sh1[d] ; k<96: x1o*sh0 ; k<128: cross(x1e, sh1)/sqrt2
    for (int idx = tid; idx < 4 * 128 * 3; idx += 256) {
        int c = idx / 384, r = idx % 384, k = r / 3, d = r % 3;
        float v = 0.f;
        if (k < 64) {
            if (c >= 1 && d == c - 1) v = xs[k];
        } else if (k < 96) {
            if (c == 0) v = xs[64 + (k - 64) * 3 + d];
        } else {
            if (c >= 1) {
                int t = c - 1, j = k - 96;
                // cross(a, e_t)_d = a[(d+1)%3]*[(d+2)%3==t] - a[(d+2)%3]*[(d+1)%3==t]
                float a1 = xs[160 + j * 3 + (d + 1) % 3];
                float a2 = xs[160 + j * 3 + (d + 2) % 3];
                v = ((((d + 2) % 3) == t) ? a1 : 0.f) - ((((d + 1) % 3) == t) ? a2 : 0.f);
                v *= INV_S2;
            }
        }
        o1o[c][k][d] = v;
    }
    // out1e[c][k][d]: k<32: cross(x1o, sh1)/sqrt2 ; k<64: x1e*sh0 ; k<80: x0o*sh1[d]
    for (int idx = tid; idx < 4 * 80 * 3; idx += 256) {
        int c = idx / 240, r = idx % 240, k = r / 3, d = r % 3;
        float v = 0.f;
        if (k < 32) {
            if (c >= 1) {
                int t = c - 1;
                float a1 = xs[64 + k * 3 + (d + 1) % 3];
                float a2 = xs[64 + k * 3 + (d + 2) % 3];
                v = ((((d + 2) % 3) == t) ? a1 : 0.f) - ((((d + 1) % 3) == t) ? a2 : 0.f);
                v *= INV_S2;
            }
        } else if (k < 64) {
            if (c == 0) v = xs[160 + (k - 32) * 3 + d];
        } else {
            if (c >= 1 && d == c - 1) v = xs[256 + (k - 64)];
        }
        o1e[c][k][d] = v;
    }
    // out0o[c][k]: k<32: (x1e·sh1)/sqrt3 ; k>=32: x0o*sh0
    for (int idx = tid; idx < 4 * 48; idx += 256) {
        int c = idx / 48, k = idx % 48;
        float v = 0.f;
        if (k < 32) { if (c >= 1) v = xs[160 + k * 3 + (c - 1)] * INV_S3; }
        else        { if (c == 0) v = xs[256 + (k - 32)]; }
        o0o[c][k] = v;
    }
    __syncthreads();

    float* zrow = Z + row * (4 * 272);

    // y0e: 4c x 64o = 256 outputs, exactly one per thread
    {
        int c = tid >> 6, o = tid & 63;
        float acc = 0.f;
        #pragma unroll 4
        for (int k = 0; k < 96; ++k) acc += o0e[c][k] * w0e[k * 64 + o];
        zrow[c * 272 + o] = acc;
    }
    // y1o: 4c x 32o x 3d = 384 outputs
    for (int idx = tid; idx < 384; idx += 256) {
        int c = idx / 96, r = idx % 96, o = r / 3, d = r % 3;
        float acc = 0.f;
        #pragma unroll 4
        for (int k = 0; k < 128; ++k) acc += o1o[c][k][d] * w1o[k * 32 + o];
        zrow[c * 272 + 64 + r] = acc;
    }
    // y1e: 384 outputs
    for (int idx = tid; idx < 384; idx += 256) {
        int c = idx / 96, r = idx % 96, o = r / 3, d = r % 3;
        float acc = 0.f;
        #pragma unroll 4
        for (int k = 0; k < 80; ++k) acc += o1e[c][k][d] * w1e[k * 32 + o];
        zrow[c * 272 + 160 + r] = acc;
    }
    // y0o: 4c x 16o = 64 outputs
    if (tid < 64) {
        int c = tid >> 4, o = tid & 15;
        float acc = 0.f;
        #pragma unroll 4
        for (int k = 0; k < 48; ++k) acc += o0o[c][k] * w0o[k * 16 + o];
        zrow[c * 272 + 256 + o] = acc;
    }
}

// out[b,m,n,o] = sum_c sh[b,m,c] * Z[b,n,c,o]
// grid: 4 b x 4 mchunks x 34 pos-blocks = 544 blocks of 256
__global__ __launch_bounds__(256) void stage_b(const float4* __restrict__ Z4,
                                               const float* __restrict__ sh,
                                               float4* __restrict__ out4) {
    __shared__ float shs[128]; // 32 m x 4 coeffs
    const int tid = threadIdx.x;
    int blk = blockIdx.x;
    int b = blk / 136;
    int rem = blk % 136;
    int mch = rem / 34;
    int pblk = rem % 34;
    int p = pblk * 256 + tid;      // [0, 8704) position within (b,m) slab, float4 units
    int n = p / 68;
    int o4 = p - n * 68;
    int m0 = mch * 32;

    if (tid < 128) shs[tid] = sh[(b * 128 + m0) * 4 + tid];
    __syncthreads();

    const float4* zr = Z4 + (size_t)((b * 128 + n) * 4) * 68 + o4;
    float4 z0 = zr[0];
    float4 z1 = zr[68];
    float4 z2 = zr[2 * 68];
    float4 z3 = zr[3 * 68];

    float4* ob = out4 + (size_t)(b * 128 + m0) * 8704 + p;
    #pragma unroll 4
    for (int j = 0; j < 32; ++j) {
        float s0 = shs[j * 4 + 0];
        float s1 = shs[j * 4 + 1];
        float s2 = shs[j * 4 + 2];
        float s3 = shs[j * 4 + 3];
        float4 v;
        v.x = s0 * z0.x + s1 * z1.x + s2 * z2.x + s3 * z3.x;
        v.y = s0 * z0.y + s1 * z1.y + s2 * z2.y + s3 * z3.y;
        v.z = s0 * z0.z + s1 * z1.z + s2 * z2.z + s3 * z3.z;
        v.w = s0 * z0.w + s1 * z1.w + s2 * z2.w + s3 * z3.w;
        ob[(size_t)j * 8704] = v;
    }
}

extern "C" void kernel_launch(void* const* d_in, const int* in_sizes, int n_in,
                              void* d_out, int out_size, void* d_ws, size_t ws_size,
                              hipStream_t stream) {
    (void)in_sizes; (void)n_in; (void)out_size; (void)ws_size;
    const float* in_ = (const float*)d_in[0];  // (4,1,128,272)
    const float* sh  = (const float*)d_in[1];  // (4,128,1,4)
    const float* w   = (const float*)d_in[2];  // (13568,)
    float* Z = (float*)d_ws;                   // 512 * 4 * 272 floats = 2.23 MB
    float* out = (float*)d_out;                // (4,128,128,272)

    stage_a<<<512, 256, 0, stream>>>(in_, w, Z);
    stage_b<<<544, 256, 0, stream>>>((const float4*)Z, sh, (float4*)out);
}

// Round 4
// 98.917 us; speedup vs baseline: 1.0663x; 1.0663x over previous
//
#include <hip/hip_runtime.h>

// M0E=64, M1O=32, M1E=32, M0O=16, IN_DIM = 272
// W flat: w0e [96][64] @0, w1o [128][32] @6144, w1e [80][32] @10240, w0o [48][16] @12800
// x row: x0e@0(64), x1o[j*3+d]@64(96), x1e@160(96), x0o@256(16)
// Z row per (b,n): [c=0..3][ y0e(64) | y1o r=o*3+d (96) | y1e (96) | y0o(16) ] = 4*272
// out[b][m][n][o]: per (b,m) slab = 128*272 = 34816 floats = 8704 float4

typedef float vfloat4 __attribute__((ext_vector_type(4)));  // native vec for nontemporal st

constexpr float INV_S3 = 0.57735026918962576f;
constexpr float INV_S2 = 0.70710678118654752f;
constexpr float SC0E = 0.10206207261596577f;   // 1/sqrt(96)
constexpr float SC1O = 0.08838834764831845f;   // 1/sqrt(128)
constexpr float SC1E = 0.11180339887498949f;   // 1/sqrt(80)
constexpr float SC0O = 0.14433756729740643f;   // 1/sqrt(48)

// Padded LDS strides to spread broadcast reads across banks
#define P0E 97
#define P1O 129
#define P1E 81
#define P0O 49

__global__ __launch_bounds__(320) void stage_a(const float* __restrict__ in_,
                                               const float* __restrict__ weight,
                                               float* __restrict__ Z) {
    __shared__ float xs[272];
    __shared__ float o0e[4 * P0E];       // [c][k<96], scaled by SC0E (and INV_S3)
    __shared__ float o1oT[12 * P1O];     // [c*3+d][k<128], scaled by SC1O (and INV_S2)
    __shared__ float o1eT[12 * P1E];     // [c*3+d][k<80], scaled by SC1E (and INV_S2)
    __shared__ float o0o[4 * P0O];       // [c][k<48], scaled by SC0O (and INV_S3)

    const int tid = threadIdx.x;
    const int row = blockIdx.x;          // b*128 + n
    const float* x = in_ + row * 272;

    if (tid < 68) ((float4*)xs)[tid] = ((const float4*)x)[tid];
    __syncthreads();

    // ---- build sparse out*[c] for sh = e_c, scales folded in ----
    for (int idx = tid; idx < 4 * 96; idx += 320) {
        int c = idx / 96, k = idx - c * 96;
        float v = 0.f;
        if (k < 64) { if (c == 0) v = xs[k]; }
        else        { if (c >= 1) v = xs[64 + (k - 64) * 3 + (c - 1)] * INV_S3; }
        o0e[c * P0E + k] = v * SC0E;
    }
    for (int idx = tid; idx < 4 * 3 * 128; idx += 320) {
        int c = idx / 384, rem = idx - c * 384, d = rem >> 7, k = rem & 127;
        float v = 0.f;
        if (k < 64) {
            if (c >= 1 && d == c - 1) v = xs[k];
        } else if (k < 96) {
            if (c == 0) v = xs[64 + (k - 64) * 3 + d];
        } else {
            if (c >= 1) {
                int t = c - 1, j = k - 96;
                float a1 = xs[160 + j * 3 + (d + 1) % 3];
                float a2 = xs[160 + j * 3 + (d + 2) % 3];
                v = ((((d + 2) % 3) == t) ? a1 : 0.f) - ((((d + 1) % 3) == t) ? a2 : 0.f);
                v *= INV_S2;
            }
        }
        o1oT[(c * 3 + d) * P1O + k] = v * SC1O;
    }
    for (int idx = tid; idx < 4 * 3 * 80; idx += 320) {
        int c = idx / 240, rem = idx - c * 240, d = rem / 80, k = rem - d * 80;
        float v = 0.f;
        if (k < 32) {
            if (c >= 1) {
                int t = c - 1;
                float a1 = xs[64 + k * 3 + (d + 1) % 3];
                float a2 = xs[64 + k * 3 + (d + 2) % 3];
                v = ((((d + 2) % 3) == t) ? a1 : 0.f) - ((((d + 1) % 3) == t) ? a2 : 0.f);
                v *= INV_S2;
            }
        } else if (k < 64) {
            if (c == 0) v = xs[160 + (k - 32) * 3 + d];
        } else {
            if (c >= 1 && d == c - 1) v = xs[256 + (k - 64)];
        }
        o1eT[(c * 3 + d) * P1E + k] = v * SC1E;
    }
    for (int idx = tid; idx < 4 * 48; idx += 320) {
        int c = idx / 48, k = idx - c * 48;
        float v = 0.f;
        if (k < 32) { if (c >= 1) v = xs[160 + k * 3 + (c - 1)] * INV_S3; }
        else        { if (c == 0) v = xs[256 + (k - 32)]; }
        o0o[c * P0O + k] = v * SC0O;
    }
    __syncthreads();

    // ---- matmul: each thread computes 4 consecutive outputs; W read from global (L2-hot) ----
    float* zrow = Z + row * 1088;

    if (tid < 64) {                       // y0e: c = tid/16, o4 = tid%16
        int c = tid >> 4, o4 = tid & 15;
        const float* wp = weight + o4 * 4;
        const float* op = o0e + c * P0E;
        float ax = 0.f, ay = 0.f, az = 0.f, aw = 0.f;
        #pragma unroll 8
        for (int k = 0; k < 96; ++k) {
            float s = op[k];
            float4 w = *(const float4*)(wp + k * 64);
            ax += s * w.x; ay += s * w.y; az += s * w.z; aw += s * w.w;
        }
        float4 r; r.x = ax; r.y = ay; r.z = az; r.w = aw;
        *(float4*)(zrow + c * 272 + o4 * 4) = r;
    } else if (tid < 160) {               // y1o: 96 tasks (c,d,o4)
        int t2 = tid - 64;
        int c = t2 / 24, r2 = t2 - c * 24, d = r2 >> 3, o4 = r2 & 7;
        const float* wp = weight + 6144 + o4 * 4;
        const float* op = o1oT + (c * 3 + d) * P1O;
        float ax = 0.f, ay = 0.f, az = 0.f, aw = 0.f;
        #pragma unroll 8
        for (int k = 0; k < 128; ++k) {
            float s = op[k];
            float4 w = *(const float4*)(wp + k * 32);
            ax += s * w.x; ay += s * w.y; az += s * w.z; aw += s * w.w;
        }
        float* zb = zrow + c * 272 + 64 + d;
        zb[(o4 * 4 + 0) * 3] = ax;
        zb[(o4 * 4 + 1) * 3] = ay;
        zb[(o4 * 4 + 2) * 3] = az;
        zb[(o4 * 4 + 3) * 3] = aw;
    } else if (tid < 256) {               // y1e: 96 tasks (c,d,o4)
        int t2 = tid - 160;
        int c = t2 / 24, r2 = t2 - c * 24, d = r2 >> 3, o4 = r2 & 7;
        const float* wp = weight + 10240 + o4 * 4;
        const float* op = o1eT + (c * 3 + d) * P1E;
        float ax = 0.f, ay = 0.f, az = 0.f, aw = 0.f;
        #pragma unroll 8
        for (int k = 0; k < 80; ++k) {
            float s = op[k];
            float4 w = *(const float4*)(wp + k * 32);
            ax += s * w.x; ay += s * w.y; az += s * w.z; aw += s * w.w;
        }
        float* zb = zrow + c * 272 + 160 + d;
        zb[(o4 * 4 + 0) * 3] = ax;
        zb[(o4 * 4 + 1) * 3] = ay;
        zb[(o4 * 4 + 2) * 3] = az;
        zb[(o4 * 4 + 3) * 3] = aw;
    } else if (tid < 272) {               // y0o: 16 tasks (c,o4)
        int t2 = tid - 256;
        int c = t2 >> 2, o4 = t2 & 3;
        const float* wp = weight + 12800 + o4 * 4;
        const float* op = o0o + c * P0O;
        float ax = 0.f, ay = 0.f, az = 0.f, aw = 0.f;
        #pragma unroll 8
        for (int k = 0; k < 48; ++k) {
            float s = op[k];
            float4 w = *(const float4*)(wp + k * 16);
            ax += s * w.x; ay += s * w.y; az += s * w.z; aw += s * w.w;
        }
        float4 r; r.x = ax; r.y = ay; r.z = az; r.w = aw;
        *(float4*)(zrow + c * 272 + 256 + o4 * 4) = r;
    }
}

// out[b,m,n,:] = sum_c sh[b,m,c] * Z[b,n,c,:]
// grid: 4 b x 8 mchunks(16 m) x 34 pos-blocks = 1088 blocks of 256
__global__ __launch_bounds__(256) void stage_b(const float4* __restrict__ Z4,
                                               const float* __restrict__ sh,
                                               vfloat4* __restrict__ out4) {
    __shared__ float shs[64];            // 16 m x 4 coeffs
    const int tid = threadIdx.x;
    int blk = blockIdx.x;
    int b = blk / 272;
    int rem = blk - b * 272;
    int mch = rem / 34;
    int pblk = rem - mch * 34;
    int p = pblk * 256 + tid;            // [0, 8704) float4 position in (b,m) slab
    int n = p / 68;
    int o4 = p - n * 68;
    int m0 = mch * 16;

    if (tid < 64) shs[tid] = sh[(b * 128 + m0) * 4 + tid];
    __syncthreads();

    const float4* zr = Z4 + (size_t)((b * 128 + n) * 4) * 68 + o4;
    float4 z0 = zr[0];
    float4 z1 = zr[68];
    float4 z2 = zr[2 * 68];
    float4 z3 = zr[3 * 68];

    vfloat4* ob = out4 + (size_t)(b * 128 + m0) * 8704 + p;
    #pragma unroll 4
    for (int j = 0; j < 16; ++j) {
        float s0 = shs[j * 4 + 0];
        float s1 = shs[j * 4 + 1];
        float s2 = shs[j * 4 + 2];
        float s3 = shs[j * 4 + 3];
        vfloat4 v;
        v.x = s0 * z0.x + s1 * z1.x + s2 * z2.x + s3 * z3.x;
        v.y = s0 * z0.y + s1 * z1.y + s2 * z2.y + s3 * z3.y;
        v.z = s0 * z0.z + s1 * z1.z + s2 * z2.z + s3 * z3.z;
        v.w = s0 * z0.w + s1 * z1.w + s2 * z2.w + s3 * z3.w;
        __builtin_nontemporal_store(v, ob + (size_t)j * 8704);
    }
}

extern "C" void kernel_launch(void* const* d_in, const int* in_sizes, int n_in,
                              void* d_out, int out_size, void* d_ws, size_t ws_size,
                              hipStream_t stream) {
    (void)in_sizes; (void)n_in; (void)out_size; (void)ws_size;
    const float* in_ = (const float*)d_in[0];  // (4,1,128,272)
    const float* sh  = (const float*)d_in[1];  // (4,128,1,4)
    const float* w   = (const float*)d_in[2];  // (13568,)
    float* Z = (float*)d_ws;                   // 512 * 1088 floats = 2.23 MB
    float* out = (float*)d_out;                // (4,128,128,272)

    stage_a<<<512, 320, 0, stream>>>(in_, w, Z);
    stage_b<<<1088, 256, 0, stream>>>((const float4*)Z, sh, (vfloat4*)out);
}